// Round 7
// baseline (441.806 us; speedup 1.0000x reference)
//
#include <hip/hip_runtime.h>
#include <math.h>

#define NC 200000
#define NT 2000
#define HH 256
#define NH_ 8
#define SCALE 0.17677669529663687f   // 32^-0.5
#define EPS 1e-5f
#define SLICE 128
#define PSLICES (NT + NC / SLICE + 1)   // upper bound on slice count
#define PSTRIDE 2056                    // 2048 cw + 8 denom

// ---------------- counting sort of cells by cluster ----------------

__global__ void k_hist(const int* __restrict__ labels, int* __restrict__ counts) {
  int i = blockIdx.x * 256 + threadIdx.x;
  if (i < NC) atomicAdd(&counts[labels[i]], 1);
}

// scan: offsets (cell prefix), soff (slice prefix) + slice_t map
__global__ void k_scan(const int* __restrict__ counts, int* __restrict__ offsets,
                       int* __restrict__ soff, int* __restrict__ slice_t) {
  int tid = threadIdx.x;
  int base = tid * 32;
  int la[32], lb[32], scnt[32];
  int sa = 0, sb = 0;
  #pragma unroll
  for (int k = 0; k < 32; k++) {
    int idx = base + k;
    int v = (idx < NT) ? counts[idx] : 0;
    la[k] = sa; lb[k] = sb;
    scnt[k] = (v + SLICE - 1) / SLICE;
    sa += v; sb += scnt[k];
  }
  int ia_ = sa, ib_ = sb;
  #pragma unroll
  for (int d = 1; d < 64; d <<= 1) {
    int oa = __shfl_up(ia_, d, 64);
    int ob = __shfl_up(ib_, d, 64);
    if (tid >= d) { ia_ += oa; ib_ += ob; }
  }
  int ea = ia_ - sa, eb = ib_ - sb;
  #pragma unroll
  for (int k = 0; k < 32; k++) {
    int idx = base + k;
    if (idx < NT) {
      offsets[idx] = ea + la[k];
      soff[idx] = eb + lb[k];
      int st = eb + lb[k];
      for (int s2 = 0; s2 < scnt[k]; s2++) slice_t[st + s2] = idx;
    }
  }
  if (tid == 63) { offsets[NT] = ia_; soff[NT] = ib_; }
}

__global__ void k_scatter(const int* __restrict__ labels, const int* __restrict__ offsets,
                          int* __restrict__ cursor, int* __restrict__ cindex) {
  int i = blockIdx.x * 256 + threadIdx.x;
  if (i < NC) {
    int c = labels[i];
    int pos = offsets[c] + atomicAdd(&cursor[c], 1);
    cindex[pos] = i;
  }
}

// ---------------- small GEMM: C[M,256] = A[M,256] @ W[256,256] + bias ----------------

__global__ __launch_bounds__(256) void k_gemm_bias(
    const float* __restrict__ A, const float* __restrict__ W,
    const float* __restrict__ bias, float* __restrict__ C, int M)
{
  __shared__ float Al[16][33];
  __shared__ float Wl[32][HH];
  int tid = threadIdx.x;
  int r0 = blockIdx.x * 16;
  float acc[16];
  #pragma unroll
  for (int r = 0; r < 16; r++) acc[r] = 0.f;
  for (int k0 = 0; k0 < HH; k0 += 32) {
    for (int e = tid; e < 16 * 32; e += 256) {
      int r = e >> 5, k = e & 31;
      int row = r0 + r;
      Al[r][k] = (row < M) ? A[(size_t)row * HH + k0 + k] : 0.f;
    }
    for (int e = tid; e < 32 * HH; e += 256) {
      int k = e >> 8, j = e & 255;
      Wl[k][j] = W[(size_t)(k0 + k) * HH + j];
    }
    __syncthreads();
    for (int k = 0; k < 32; k++) {
      float w = Wl[k][tid];
      #pragma unroll
      for (int r = 0; r < 16; r++) acc[r] += Al[r][k] * w;
    }
    __syncthreads();
  }
  float bj = bias[tid];
  #pragma unroll
  for (int r = 0; r < 16; r++) {
    int row = r0 + r;
    if (row < M) C[(size_t)row * HH + tid] = acc[r] + bj;
  }
}

// ---------------- Qproj + bkq (fused) ----------------

__global__ __launch_bounds__(256) void k_qproj(
    const float* __restrict__ Q, const float* __restrict__ Wk,
    const float* __restrict__ bk, float* __restrict__ Qproj,
    float* __restrict__ bkq)
{
  __shared__ float Al[64][33];
  __shared__ float Bl[32][257];
  int h = blockIdx.x & 7, tb = blockIdx.x >> 3;
  int t0 = tb * 64;
  int tid = threadIdx.x;
  for (int e = tid; e < 64 * 32; e += 256) {
    int r = e >> 5, d = e & 31;
    int t = t0 + r;
    Al[r][d] = (t < NT) ? Q[(size_t)t * HH + h * 32 + d] * SCALE : 0.f;
  }
  for (int e = tid; e < 256 * 32; e += 256) {
    int j = e >> 5, d = e & 31;
    Bl[d][j] = Wk[(size_t)j * HH + h * 32 + d];
  }
  __syncthreads();
  float acc[64];
  #pragma unroll
  for (int r = 0; r < 64; r++) acc[r] = 0.f;
  for (int d = 0; d < 32; d++) {
    float b = Bl[d][tid];
    #pragma unroll
    for (int r = 0; r < 64; r++) acc[r] += Al[r][d] * b;
  }
  for (int r = 0; r < 64; r++) {
    int t = t0 + r;
    if (t < NT) Qproj[((size_t)t * NH_ + h) * HH + tid] = acc[r];
  }
  if (tid < 64) {
    int t = t0 + tid;
    if (t < NT) {
      float s = 0.f;
      #pragma unroll
      for (int d = 0; d < 32; d++) s += Al[tid][d] * bk[h * 32 + d];
      bkq[t * NH_ + h] = s;
    }
  }
}

// ---------------- per-slice attention: 1KB-burst LDS row staging ----------------
// Memory: a wave loads ONE FULL cell row per instruction (lane l -> bytes 16l..16l+15,
// 1 KB sequential burst), stages 4 rows/group into its private LDS slot via
// ds_write_b128 (in-order within wave -> no barrier, single buffer).
// Compute (verified R6 layout): lane=(hg=lane&3 -> heads 2hg,2hg+1; kc=lane>>2 ->
// chunks i*16+kc), x via 4x ds_read_b128, 8 shfl reduce, exp, PV accumulate in regs.
// Next group's global loads issue before current group's compute (software pipeline).

#define GRP 4
#define ROWF 260   // padded row stride in floats (1040 B, breaks 1KB bank alias)

__global__ __launch_bounds__(256) void k_cellslice(
    const float* __restrict__ cell, const int* __restrict__ cindex,
    const int* __restrict__ offsets, const int* __restrict__ soff,
    const int* __restrict__ slice_t,
    const float* __restrict__ Qproj, const float* __restrict__ bkq,
    float* __restrict__ Pbuf)
{
  __shared__ int   cidx[SLICE];              // 512 B
  __shared__ float xbuf[4][GRP][ROWF];       // 16.6 KB: per-wave row slots
  __shared__ float cwlds[NH_][HH];           // 8 KB
  __shared__ float red[4][NH_];

  int s = blockIdx.x;
  if (s >= soff[NT]) return;
  int t = slice_t[s];
  int l = s - soff[t];
  int c0 = offsets[t] + l * SLICE;
  int c1 = min(c0 + SLICE, offsets[t + 1]);
  int nc = c1 - c0;

  int tid = threadIdx.x;
  int w = tid >> 6, lane = tid & 63;
  int hg = lane & 3, kc = lane >> 2;

  if (tid < SLICE) cidx[tid] = cindex[min(c0 + tid, c1 - 1)];

  // qp registers: 2 heads x 4 float4 (chunk i*16+kc)
  const float* qpb = Qproj + (size_t)t * NH_ * HH;
  float4 qp0[4], qp1[4];
  #pragma unroll
  for (int i = 0; i < 4; i++) {
    qp0[i] = *reinterpret_cast<const float4*>(qpb + (2 * hg) * HH + (i * 16 + kc) * 4);
    qp1[i] = *reinterpret_cast<const float4*>(qpb + (2 * hg + 1) * HH + (i * 16 + kc) * 4);
  }
  float bq0 = bkq[t * NH_ + 2 * hg];
  float bq1 = bkq[t * NH_ + 2 * hg + 1];

  float4 cw0[4], cw1[4];
  #pragma unroll
  for (int i = 0; i < 4; i++) {
    cw0[i] = make_float4(0.f, 0.f, 0.f, 0.f);
    cw1[i] = make_float4(0.f, 0.f, 0.f, 0.f);
  }
  float d0 = 0.f, d1 = 0.f;

  __syncthreads();   // cidx ready

  float (*myx)[ROWF] = xbuf[w];
  int base = w * GRP;
  float4 st[GRP];

  // prologue: load + stage group 0 (clamped indices; padding masked later)
  #pragma unroll
  for (int r = 0; r < GRP; r++)
    st[r] = *reinterpret_cast<const float4*>(
        &cell[(size_t)cidx[min(base + r, nc - 1)] * HH + lane * 4]);
  #pragma unroll
  for (int r = 0; r < GRP; r++)
    *reinterpret_cast<float4*>(&myx[r][lane * 4]) = st[r];

  for (int gb = base; gb < nc; gb += 16) {
    int gn = gb + 16;
    bool more = gn < nc;
    if (more) {
      #pragma unroll
      for (int r = 0; r < GRP; r++)
        st[r] = *reinterpret_cast<const float4*>(
            &cell[(size_t)cidx[min(gn + r, nc - 1)] * HH + lane * 4]);
    }
    // compute 4 cells from LDS
    #pragma unroll
    for (int c = 0; c < GRP; c++) {
      float4 x0 = *reinterpret_cast<float4*>(&myx[c][(0 * 16 + kc) * 4]);
      float4 x1 = *reinterpret_cast<float4*>(&myx[c][(1 * 16 + kc) * 4]);
      float4 x2 = *reinterpret_cast<float4*>(&myx[c][(2 * 16 + kc) * 4]);
      float4 x3 = *reinterpret_cast<float4*>(&myx[c][(3 * 16 + kc) * 4]);
      float s0 = x0.x * qp0[0].x + x0.y * qp0[0].y + x0.z * qp0[0].z + x0.w * qp0[0].w
               + x1.x * qp0[1].x + x1.y * qp0[1].y + x1.z * qp0[1].z + x1.w * qp0[1].w
               + x2.x * qp0[2].x + x2.y * qp0[2].y + x2.z * qp0[2].z + x2.w * qp0[2].w
               + x3.x * qp0[3].x + x3.y * qp0[3].y + x3.z * qp0[3].z + x3.w * qp0[3].w;
      float s1 = x0.x * qp1[0].x + x0.y * qp1[0].y + x0.z * qp1[0].z + x0.w * qp1[0].w
               + x1.x * qp1[1].x + x1.y * qp1[1].y + x1.z * qp1[1].z + x1.w * qp1[1].w
               + x2.x * qp1[2].x + x2.y * qp1[2].y + x2.z * qp1[2].z + x2.w * qp1[2].w
               + x3.x * qp1[3].x + x3.y * qp1[3].y + x3.z * qp1[3].z + x3.w * qp1[3].w;
      #pragma unroll
      for (int d = 4; d < 64; d <<= 1) {
        s0 += __shfl_xor(s0, d, 64);
        s1 += __shfl_xor(s1, d, 64);
      }
      float e0 = __expf(s0 + bq0);
      float e1 = __expf(s1 + bq1);
      if (gb + c >= nc) { e0 = 0.f; e1 = 0.f; }
      d0 += e0; d1 += e1;
      cw0[0].x += e0 * x0.x; cw0[0].y += e0 * x0.y; cw0[0].z += e0 * x0.z; cw0[0].w += e0 * x0.w;
      cw0[1].x += e0 * x1.x; cw0[1].y += e0 * x1.y; cw0[1].z += e0 * x1.z; cw0[1].w += e0 * x1.w;
      cw0[2].x += e0 * x2.x; cw0[2].y += e0 * x2.y; cw0[2].z += e0 * x2.z; cw0[2].w += e0 * x2.w;
      cw0[3].x += e0 * x3.x; cw0[3].y += e0 * x3.y; cw0[3].z += e0 * x3.z; cw0[3].w += e0 * x3.w;
      cw1[0].x += e1 * x0.x; cw1[0].y += e1 * x0.y; cw1[0].z += e1 * x0.z; cw1[0].w += e1 * x0.w;
      cw1[1].x += e1 * x1.x; cw1[1].y += e1 * x1.y; cw1[1].z += e1 * x1.z; cw1[1].w += e1 * x1.w;
      cw1[2].x += e1 * x2.x; cw1[2].y += e1 * x2.y; cw1[2].z += e1 * x2.z; cw1[2].w += e1 * x2.w;
      cw1[3].x += e1 * x3.x; cw1[3].y += e1 * x3.y; cw1[3].z += e1 * x3.z; cw1[3].w += e1 * x3.w;
    }
    // stage next group (in-order DS within wave: safe after this group's reads)
    if (more) {
      #pragma unroll
      for (int r = 0; r < GRP; r++)
        *reinterpret_cast<float4*>(&myx[r][lane * 4]) = st[r];
    }
  }

  // merge 4 waves' cw into LDS
  if (w == 0) {
    #pragma unroll
    for (int i = 0; i < 4; i++) {
      *reinterpret_cast<float4*>(&cwlds[2 * hg][(i * 16 + kc) * 4]) = cw0[i];
      *reinterpret_cast<float4*>(&cwlds[2 * hg + 1][(i * 16 + kc) * 4]) = cw1[i];
    }
  }
  if (kc == 0) { red[w][2 * hg] = d0; red[w][2 * hg + 1] = d1; }
  __syncthreads();
  #pragma unroll
  for (int ww = 1; ww < 4; ww++) {
    if (w == ww) {
      #pragma unroll
      for (int i = 0; i < 4; i++) {
        float4 a = *reinterpret_cast<float4*>(&cwlds[2 * hg][(i * 16 + kc) * 4]);
        a.x += cw0[i].x; a.y += cw0[i].y; a.z += cw0[i].z; a.w += cw0[i].w;
        *reinterpret_cast<float4*>(&cwlds[2 * hg][(i * 16 + kc) * 4]) = a;
        float4 b = *reinterpret_cast<float4*>(&cwlds[2 * hg + 1][(i * 16 + kc) * 4]);
        b.x += cw1[i].x; b.y += cw1[i].y; b.z += cw1[i].z; b.w += cw1[i].w;
        *reinterpret_cast<float4*>(&cwlds[2 * hg + 1][(i * 16 + kc) * 4]) = b;
      }
    }
    __syncthreads();
  }

  float* pb = Pbuf + (size_t)s * PSTRIDE;
  #pragma unroll
  for (int h = 0; h < NH_; h++) pb[h * HH + tid] = cwlds[h][tid];
  if (tid < NH_) pb[2048 + tid] = red[0][tid] + red[1][tid] + red[2][tid] + red[3][tid];
}

// ---------------- fused tissue chain (with slice reduction) ----------------

#define TCH 4

__global__ __launch_bounds__(256) void k_tissuechain(
    const float* __restrict__ tissue, const int* __restrict__ counts,
    const float* __restrict__ Pbuf, const int* __restrict__ soff,
    const float* __restrict__ Wv, const float* __restrict__ bv,
    const float* __restrict__ Wo, const float* __restrict__ bo,
    const float* __restrict__ Wvtd, const float* __restrict__ bvtd,
    const float* __restrict__ Wotd, const float* __restrict__ botd,
    const float* __restrict__ lng, const float* __restrict__ lnb,
    float* __restrict__ td, float* __restrict__ out_tissue)
{
  __shared__ float s_cwn[TCH][NH_ * HH];
  __shared__ float s_a[TCH][HH];
  __shared__ float s_tu[TCH][HH];
  __shared__ float s_tmp[TCH][HH];
  __shared__ float s_red[2][4];
  __shared__ float s_dinv[TCH][NH_];
  int t0 = blockIdx.x * TCH;
  int j = threadIdx.x;
  int h = j >> 5;

  if (j < TCH * NH_) {
    int t = j >> 3, hh = j & 7;
    int s0 = soff[t0 + t], s1 = soff[t0 + t + 1];
    float d = 0.f;
    for (int q = s0; q < s1; q++) d += Pbuf[(size_t)q * PSTRIDE + 2048 + hh];
    s_dinv[t][hh] = (s1 > s0) ? 1.f / d : 0.f;
  }
  __syncthreads();

  for (int e = j; e < TCH * NH_ * HH; e += 256) {
    int t = e >> 11, c = e & 2047, hh = c >> 8;
    int s0 = soff[t0 + t], s1 = soff[t0 + t + 1];
    float a = 0.f;
    for (int q = s0; q < s1; q++) a += Pbuf[(size_t)q * PSTRIDE + c];
    s_cwn[t][c] = a * s_dinv[t][hh];
  }
  __syncthreads();

  float acc[TCH];
  #pragma unroll
  for (int t = 0; t < TCH; t++) acc[t] = 0.f;
  for (int k = 0; k < HH; k++) {
    float w = Wv[(size_t)k * HH + j];
    #pragma unroll
    for (int t = 0; t < TCH; t++) acc[t] += s_cwn[t][h * HH + k] * w;
  }
  {
    float bj = bv[j];
    #pragma unroll
    for (int t = 0; t < TCH; t++) s_a[t][j] = acc[t] + bj;
  }
  __syncthreads();

  #pragma unroll
  for (int t = 0; t < TCH; t++) acc[t] = 0.f;
  for (int k = 0; k < HH; k++) {
    float w = Wo[(size_t)k * HH + j];
    #pragma unroll
    for (int t = 0; t < TCH; t++) acc[t] += s_a[t][k] * w;
  }
  {
    float bj = bo[j];
    #pragma unroll
    for (int t = 0; t < TCH; t++) {
      int tt = t0 + t;
      s_tu[t][j] = (counts[tt] > 0) ? (acc[t] + bj) : tissue[(size_t)tt * HH + j];
    }
  }
  __syncthreads();

  #pragma unroll
  for (int t = 0; t < TCH; t++) acc[t] = 0.f;
  for (int k = 0; k < HH; k++) {
    float w = Wvtd[(size_t)k * HH + j];
    #pragma unroll
    for (int t = 0; t < TCH; t++) acc[t] += s_tu[t][k] * w;
  }
  {
    float bj = bvtd[j];
    #pragma unroll
    for (int t = 0; t < TCH; t++) s_tmp[t][j] = acc[t] + bj;
  }
  __syncthreads();

  #pragma unroll
  for (int t = 0; t < TCH; t++) acc[t] = 0.f;
  for (int k = 0; k < HH; k++) {
    float w = Wotd[(size_t)k * HH + j];
    #pragma unroll
    for (int t = 0; t < TCH; t++) acc[t] += s_tmp[t][k] * w;
  }
  {
    float bj = botd[j];
    #pragma unroll
    for (int t = 0; t < TCH; t++) td[(size_t)(t0 + t) * HH + j] = acc[t] + bj;
  }

  float gj = lng[j], bj2 = lnb[j];
  for (int t = 0; t < TCH; t++) {
    float y = tissue[(size_t)(t0 + t) * HH + j] + s_tu[t][j];
    float s1 = y, s2 = y * y;
    #pragma unroll
    for (int d = 1; d < 64; d <<= 1) { s1 += __shfl_xor(s1, d, 64); s2 += __shfl_xor(s2, d, 64); }
    int wv_ = j >> 6, ln_ = j & 63;
    __syncthreads();
    if (ln_ == 0) { s_red[0][wv_] = s1; s_red[1][wv_] = s2; }
    __syncthreads();
    s1 = s_red[0][0] + s_red[0][1] + s_red[0][2] + s_red[0][3];
    s2 = s_red[1][0] + s_red[1][1] + s_red[1][2] + s_red[1][3];
    float mean = s1 * (1.f / 256.f);
    float var = s2 * (1.f / 256.f) - mean * mean;
    float inv = rsqrtf(var + EPS);
    out_tissue[(size_t)(t0 + t) * HH + j] = (y - mean) * inv * gj + bj2;
  }
}

// ---------------- final: cell_out = LN(cell + td[label]), grid-stride, 2-row ILP ----------------

#define COB 4096

__global__ __launch_bounds__(256) void k_cellout(
    const float* __restrict__ cell, const float* __restrict__ td,
    const int* __restrict__ labels,
    const float* __restrict__ lng, const float* __restrict__ lnb,
    float* __restrict__ out)
{
  int lane = threadIdx.x & 63;
  float4 gv = *reinterpret_cast<const float4*>(&lng[lane * 4]);
  float4 bvv = *reinterpret_cast<const float4*>(&lnb[lane * 4]);
  const int stride = COB * 4;
  int wid = blockIdx.x * 4 + (threadIdx.x >> 6);
  for (int row = wid; row < NC; row += 2 * stride) {
    int rowB = row + stride;
    bool hasB = rowB < NC;
    int cA = labels[row];
    float4 xA = *reinterpret_cast<const float4*>(&cell[(size_t)row * HH + lane * 4]);
    float4 uA = *reinterpret_cast<const float4*>(&td[(size_t)cA * HH + lane * 4]);
    float4 xB, uB;
    if (hasB) {
      int cB = labels[rowB];
      xB = *reinterpret_cast<const float4*>(&cell[(size_t)rowB * HH + lane * 4]);
      uB = *reinterpret_cast<const float4*>(&td[(size_t)cB * HH + lane * 4]);
    }
    {
      float y0 = xA.x + uA.x, y1 = xA.y + uA.y, y2 = xA.z + uA.z, y3 = xA.w + uA.w;
      float s1 = y0 + y1 + y2 + y3;
      float s2 = y0 * y0 + y1 * y1 + y2 * y2 + y3 * y3;
      #pragma unroll
      for (int d = 1; d < 64; d <<= 1) { s1 += __shfl_xor(s1, d, 64); s2 += __shfl_xor(s2, d, 64); }
      float mean = s1 * (1.f / 256.f);
      float var = s2 * (1.f / 256.f) - mean * mean;
      float inv = rsqrtf(var + EPS);
      float4 o;
      o.x = (y0 - mean) * inv * gv.x + bvv.x;
      o.y = (y1 - mean) * inv * gv.y + bvv.y;
      o.z = (y2 - mean) * inv * gv.z + bvv.z;
      o.w = (y3 - mean) * inv * gv.w + bvv.w;
      *reinterpret_cast<float4*>(&out[(size_t)row * HH + lane * 4]) = o;
    }
    if (hasB) {
      float y0 = xB.x + uB.x, y1 = xB.y + uB.y, y2 = xB.z + uB.z, y3 = xB.w + uB.w;
      float s1 = y0 + y1 + y2 + y3;
      float s2 = y0 * y0 + y1 * y1 + y2 * y2 + y3 * y3;
      #pragma unroll
      for (int d = 1; d < 64; d <<= 1) { s1 += __shfl_xor(s1, d, 64); s2 += __shfl_xor(s2, d, 64); }
      float mean = s1 * (1.f / 256.f);
      float var = s2 * (1.f / 256.f) - mean * mean;
      float inv = rsqrtf(var + EPS);
      float4 o;
      o.x = (y0 - mean) * inv * gv.x + bvv.x;
      o.y = (y1 - mean) * inv * gv.y + bvv.y;
      o.z = (y2 - mean) * inv * gv.z + bvv.z;
      o.w = (y3 - mean) * inv * gv.w + bvv.w;
      *reinterpret_cast<float4*>(&out[(size_t)rowB * HH + lane * 4]) = o;
    }
  }
}

// ---------------- launch ----------------

extern "C" void kernel_launch(void* const* d_in, const int* in_sizes, int n_in,
                              void* d_out, int out_size, void* d_ws, size_t ws_size,
                              hipStream_t stream) {
  const float* cell   = (const float*)d_in[0];
  const float* tissue = (const float*)d_in[1];
  const int*   labels = (const int*)d_in[2];
  const float* Wq = (const float*)d_in[4];  const float* bq = (const float*)d_in[5];
  const float* Wk = (const float*)d_in[6];  const float* bk = (const float*)d_in[7];
  const float* Wv = (const float*)d_in[8];  const float* bv = (const float*)d_in[9];
  const float* Wo = (const float*)d_in[10]; const float* bo = (const float*)d_in[11];
  const float* Wvtd = (const float*)d_in[12]; const float* bvtd = (const float*)d_in[13];
  const float* Wotd = (const float*)d_in[14]; const float* botd = (const float*)d_in[15];
  const float* lncg = (const float*)d_in[16]; const float* lncb = (const float*)d_in[17];
  const float* lntg = (const float*)d_in[18]; const float* lntb = (const float*)d_in[19];
  float* out_cell   = (float*)d_out;
  float* out_tissue = (float*)d_out + (size_t)NC * HH;

  char* w = (char*)d_ws;
  auto take = [&](size_t bytes) { void* p = (void*)w; w += (bytes + 255) & ~(size_t)255; return p; };
  int*   counts  = (int*)take((size_t)NT * 4);
  int*   cursor  = (int*)take((size_t)NT * 4);
  int*   offsets = (int*)take((size_t)(NT + 1) * 4);
  int*   soff    = (int*)take((size_t)(NT + 1) * 4);
  int*   slice_t = (int*)take((size_t)PSLICES * 4);
  int*   cindex  = (int*)take((size_t)NC * 4);
  float* Q       = (float*)take((size_t)NT * HH * 4);
  float* Qproj   = (float*)take((size_t)NT * NH_ * HH * 4);
  float* bkq     = (float*)take((size_t)NT * NH_ * 4);
  float* td      = (float*)take((size_t)NT * HH * 4);
  float* Pbuf    = (float*)take((size_t)PSLICES * PSTRIDE * 4);   // ~29 MB

  hipMemsetAsync(counts, 0, 16384, stream);

  const int CB = (NC + 255) / 256;
  k_hist<<<CB, 256, 0, stream>>>(labels, counts);
  k_scan<<<1, 64, 0, stream>>>(counts, offsets, soff, slice_t);
  k_scatter<<<CB, 256, 0, stream>>>(labels, offsets, cursor, cindex);

  k_gemm_bias<<<(NT + 15) / 16, 256, 0, stream>>>(tissue, Wq, bq, Q, NT);
  k_qproj<<<8 * ((NT + 63) / 64), 256, 0, stream>>>(Q, Wk, bk, Qproj, bkq);

  k_cellslice<<<PSLICES, 256, 0, stream>>>(cell, cindex, offsets, soff, slice_t,
                                           Qproj, bkq, Pbuf);

  k_tissuechain<<<NT / TCH, 256, 0, stream>>>(tissue, counts, Pbuf, soff,
      Wv, bv, Wo, bo, Wvtd, bvtd, Wotd, botd, lntg, lntb, td, out_tissue);

  k_cellout<<<COB, 256, 0, stream>>>(cell, td, labels, lncg, lncb, out_cell);
}

// Round 8
// 435.372 us; speedup vs baseline: 1.0148x; 1.0148x over previous
//
#include <hip/hip_runtime.h>
#include <math.h>

#define NC 200000
#define NT 2000
#define HH 256
#define NH_ 8
#define SCALE 0.17677669529663687f   // 32^-0.5
#define EPS 1e-5f
#define SLICE 128
#define PSLICES (NT + NC / SLICE + 1)   // upper bound on slice count
#define PSTRIDE 2056                    // 2048 cw + 8 denom

// ---------------- counting sort of cells by cluster ----------------

__global__ void k_hist(const int* __restrict__ labels, int* __restrict__ counts) {
  int i = blockIdx.x * 256 + threadIdx.x;
  if (i < NC) atomicAdd(&counts[labels[i]], 1);
}

// scan: offsets (cell prefix), soff (slice prefix) + slice_t map
__global__ void k_scan(const int* __restrict__ counts, int* __restrict__ offsets,
                       int* __restrict__ soff, int* __restrict__ slice_t) {
  int tid = threadIdx.x;
  int base = tid * 32;
  int la[32], lb[32], scnt[32];
  int sa = 0, sb = 0;
  #pragma unroll
  for (int k = 0; k < 32; k++) {
    int idx = base + k;
    int v = (idx < NT) ? counts[idx] : 0;
    la[k] = sa; lb[k] = sb;
    scnt[k] = (v + SLICE - 1) / SLICE;
    sa += v; sb += scnt[k];
  }
  int ia_ = sa, ib_ = sb;
  #pragma unroll
  for (int d = 1; d < 64; d <<= 1) {
    int oa = __shfl_up(ia_, d, 64);
    int ob = __shfl_up(ib_, d, 64);
    if (tid >= d) { ia_ += oa; ib_ += ob; }
  }
  int ea = ia_ - sa, eb = ib_ - sb;
  #pragma unroll
  for (int k = 0; k < 32; k++) {
    int idx = base + k;
    if (idx < NT) {
      offsets[idx] = ea + la[k];
      soff[idx] = eb + lb[k];
      int st = eb + lb[k];
      for (int s2 = 0; s2 < scnt[k]; s2++) slice_t[st + s2] = idx;
    }
  }
  if (tid == 63) { offsets[NT] = ia_; soff[NT] = ib_; }
}

// ---------------- bf16 pack/unpack ----------------

__device__ inline unsigned pk2(float a, float b) {
  unsigned ua = (__float_as_uint(a) + 0x8000u) >> 16;
  unsigned ub = (__float_as_uint(b) + 0x8000u) & 0xFFFF0000u;
  return ua | ub;
}
__device__ inline float lo16(unsigned u) { return __uint_as_float(u << 16); }
__device__ inline float hi16(unsigned u) { return __uint_as_float(u & 0xFFFF0000u); }

// ---------------- sort+convert: coalesced read, bf16 scatter-write to sorted order ----------------

#define SCVB 2048

__global__ __launch_bounds__(256) void k_sortcvt(
    const float* __restrict__ cell, const int* __restrict__ labels,
    const int* __restrict__ offsets, int* __restrict__ cursor,
    unsigned short* __restrict__ cellb)
{
  int lane = threadIdx.x & 63;
  int w = blockIdx.x * 4 + (threadIdx.x >> 6);
  const int nw = SCVB * 4;
  for (int i = w; i < NC; i += nw) {
    int pos = 0;
    if (lane == 0) {
      int c = labels[i];
      pos = offsets[c] + atomicAdd(&cursor[c], 1);
    }
    pos = __shfl(pos, 0, 64);
    float4 x = *reinterpret_cast<const float4*>(&cell[(size_t)i * HH + lane * 4]);
    uint2 o;
    o.x = pk2(x.x, x.y);
    o.y = pk2(x.z, x.w);
    *reinterpret_cast<uint2*>(&cellb[(size_t)pos * HH + lane * 4]) = o;
  }
}

// ---------------- small GEMM: C[M,256] = A[M,256] @ W[256,256] + bias ----------------

__global__ __launch_bounds__(256) void k_gemm_bias(
    const float* __restrict__ A, const float* __restrict__ W,
    const float* __restrict__ bias, float* __restrict__ C, int M)
{
  __shared__ float Al[16][33];
  __shared__ float Wl[32][HH];
  int tid = threadIdx.x;
  int r0 = blockIdx.x * 16;
  float acc[16];
  #pragma unroll
  for (int r = 0; r < 16; r++) acc[r] = 0.f;
  for (int k0 = 0; k0 < HH; k0 += 32) {
    for (int e = tid; e < 16 * 32; e += 256) {
      int r = e >> 5, k = e & 31;
      int row = r0 + r;
      Al[r][k] = (row < M) ? A[(size_t)row * HH + k0 + k] : 0.f;
    }
    for (int e = tid; e < 32 * HH; e += 256) {
      int k = e >> 8, j = e & 255;
      Wl[k][j] = W[(size_t)(k0 + k) * HH + j];
    }
    __syncthreads();
    for (int k = 0; k < 32; k++) {
      float w = Wl[k][tid];
      #pragma unroll
      for (int r = 0; r < 16; r++) acc[r] += Al[r][k] * w;
    }
    __syncthreads();
  }
  float bj = bias[tid];
  #pragma unroll
  for (int r = 0; r < 16; r++) {
    int row = r0 + r;
    if (row < M) C[(size_t)row * HH + tid] = acc[r] + bj;
  }
}

// ---------------- Qproj + bkq (fused) ----------------

__global__ __launch_bounds__(256) void k_qproj(
    const float* __restrict__ Q, const float* __restrict__ Wk,
    const float* __restrict__ bk, float* __restrict__ Qproj,
    float* __restrict__ bkq)
{
  __shared__ float Al[64][33];
  __shared__ float Bl[32][257];
  int h = blockIdx.x & 7, tb = blockIdx.x >> 3;
  int t0 = tb * 64;
  int tid = threadIdx.x;
  for (int e = tid; e < 64 * 32; e += 256) {
    int r = e >> 5, d = e & 31;
    int t = t0 + r;
    Al[r][d] = (t < NT) ? Q[(size_t)t * HH + h * 32 + d] * SCALE : 0.f;
  }
  for (int e = tid; e < 256 * 32; e += 256) {
    int j = e >> 5, d = e & 31;
    Bl[d][j] = Wk[(size_t)j * HH + h * 32 + d];
  }
  __syncthreads();
  float acc[64];
  #pragma unroll
  for (int r = 0; r < 64; r++) acc[r] = 0.f;
  for (int d = 0; d < 32; d++) {
    float b = Bl[d][tid];
    #pragma unroll
    for (int r = 0; r < 64; r++) acc[r] += Al[r][d] * b;
  }
  for (int r = 0; r < 64; r++) {
    int t = t0 + r;
    if (t < NT) Qproj[((size_t)t * NH_ + h) * HH + tid] = acc[r];
  }
  if (tid < 64) {
    int t = t0 + tid;
    if (t < NT) {
      float s = 0.f;
      #pragma unroll
      for (int d = 0; d < 32; d++) s += Al[tid][d] * bk[h * 32 + d];
      bkq[t * NH_ + h] = s;
    }
  }
}

// ---------------- per-slice attention: CONTIGUOUS bf16 rows, register-resident ----------------
// Slice rows are contiguous (sorted copy): streaming reads, no gather, no cindex.
// lane = (hg=lane&3 -> heads 2hg,2hg+1; kc=lane>>2 -> chunks i*16+kc).
// Per cell: 4 uint2 loads (bf16x4), unpack, dual-head dot, 8 shfl reduce, exp,
// PV accumulate in regs. 1-deep prefetch of next cell.

__global__ __launch_bounds__(256) void k_cellslice(
    const unsigned short* __restrict__ cellb,
    const int* __restrict__ offsets, const int* __restrict__ soff,
    const int* __restrict__ slice_t,
    const float* __restrict__ Qproj, const float* __restrict__ bkq,
    float* __restrict__ Pbuf)
{
  __shared__ float cwlds[NH_][HH];
  __shared__ float red[4][NH_];

  int s = blockIdx.x;
  if (s >= soff[NT]) return;
  int t = slice_t[s];
  int l = s - soff[t];
  int c0 = offsets[t] + l * SLICE;
  int c1 = min(c0 + SLICE, offsets[t + 1]);
  int nc = c1 - c0;

  int tid = threadIdx.x;
  int w = tid >> 6, lane = tid & 63;
  int hg = lane & 3, kc = lane >> 2;

  const float* qpb = Qproj + (size_t)t * NH_ * HH;
  float4 qp0[4], qp1[4];
  #pragma unroll
  for (int i = 0; i < 4; i++) {
    qp0[i] = *reinterpret_cast<const float4*>(qpb + (2 * hg) * HH + (i * 16 + kc) * 4);
    qp1[i] = *reinterpret_cast<const float4*>(qpb + (2 * hg + 1) * HH + (i * 16 + kc) * 4);
  }
  float bq0 = bkq[t * NH_ + 2 * hg];
  float bq1 = bkq[t * NH_ + 2 * hg + 1];

  float4 cw0[4], cw1[4];
  #pragma unroll
  for (int i = 0; i < 4; i++) {
    cw0[i] = make_float4(0.f, 0.f, 0.f, 0.f);
    cw1[i] = make_float4(0.f, 0.f, 0.f, 0.f);
  }
  float d0 = 0.f, d1 = 0.f;

  uint2 xv[4], nv[4];
  {
    const uint2* p = reinterpret_cast<const uint2*>(cellb + (size_t)(c0 + min(w, nc - 1)) * HH);
    #pragma unroll
    for (int i = 0; i < 4; i++) xv[i] = p[i * 16 + kc];
  }

  for (int ic = w; ic < nc; ic += 4) {
    int icn = min(ic + 4, nc - 1);
    const uint2* pn = reinterpret_cast<const uint2*>(cellb + (size_t)(c0 + icn) * HH);
    #pragma unroll
    for (int i = 0; i < 4; i++) nv[i] = pn[i * 16 + kc];

    float4 x[4];
    #pragma unroll
    for (int i = 0; i < 4; i++)
      x[i] = make_float4(lo16(xv[i].x), hi16(xv[i].x), lo16(xv[i].y), hi16(xv[i].y));

    float s0 = 0.f, s1 = 0.f;
    #pragma unroll
    for (int i = 0; i < 4; i++) {
      s0 += x[i].x * qp0[i].x + x[i].y * qp0[i].y + x[i].z * qp0[i].z + x[i].w * qp0[i].w;
      s1 += x[i].x * qp1[i].x + x[i].y * qp1[i].y + x[i].z * qp1[i].z + x[i].w * qp1[i].w;
    }
    #pragma unroll
    for (int d = 4; d < 64; d <<= 1) {
      s0 += __shfl_xor(s0, d, 64);
      s1 += __shfl_xor(s1, d, 64);
    }
    float e0 = __expf(s0 + bq0);
    float e1 = __expf(s1 + bq1);
    d0 += e0; d1 += e1;
    #pragma unroll
    for (int i = 0; i < 4; i++) {
      cw0[i].x += e0 * x[i].x; cw0[i].y += e0 * x[i].y;
      cw0[i].z += e0 * x[i].z; cw0[i].w += e0 * x[i].w;
      cw1[i].x += e1 * x[i].x; cw1[i].y += e1 * x[i].y;
      cw1[i].z += e1 * x[i].z; cw1[i].w += e1 * x[i].w;
    }
    #pragma unroll
    for (int i = 0; i < 4; i++) xv[i] = nv[i];
  }

  // merge 4 waves' cw into LDS
  if (w == 0) {
    #pragma unroll
    for (int i = 0; i < 4; i++) {
      *reinterpret_cast<float4*>(&cwlds[2 * hg][(i * 16 + kc) * 4]) = cw0[i];
      *reinterpret_cast<float4*>(&cwlds[2 * hg + 1][(i * 16 + kc) * 4]) = cw1[i];
    }
  }
  if (kc == 0) { red[w][2 * hg] = d0; red[w][2 * hg + 1] = d1; }
  __syncthreads();
  #pragma unroll
  for (int ww = 1; ww < 4; ww++) {
    if (w == ww) {
      #pragma unroll
      for (int i = 0; i < 4; i++) {
        float4 a = *reinterpret_cast<float4*>(&cwlds[2 * hg][(i * 16 + kc) * 4]);
        a.x += cw0[i].x; a.y += cw0[i].y; a.z += cw0[i].z; a.w += cw0[i].w;
        *reinterpret_cast<float4*>(&cwlds[2 * hg][(i * 16 + kc) * 4]) = a;
        float4 b = *reinterpret_cast<float4*>(&cwlds[2 * hg + 1][(i * 16 + kc) * 4]);
        b.x += cw1[i].x; b.y += cw1[i].y; b.z += cw1[i].z; b.w += cw1[i].w;
        *reinterpret_cast<float4*>(&cwlds[2 * hg + 1][(i * 16 + kc) * 4]) = b;
      }
    }
    __syncthreads();
  }

  float* pb = Pbuf + (size_t)s * PSTRIDE;
  #pragma unroll
  for (int h = 0; h < NH_; h++) pb[h * HH + tid] = cwlds[h][tid];
  if (tid < NH_) pb[2048 + tid] = red[0][tid] + red[1][tid] + red[2][tid] + red[3][tid];
}

// ---------------- fused tissue chain (with slice reduction) ----------------

#define TCH 4

__global__ __launch_bounds__(256) void k_tissuechain(
    const float* __restrict__ tissue, const int* __restrict__ counts,
    const float* __restrict__ Pbuf, const int* __restrict__ soff,
    const float* __restrict__ Wv, const float* __restrict__ bv,
    const float* __restrict__ Wo, const float* __restrict__ bo,
    const float* __restrict__ Wvtd, const float* __restrict__ bvtd,
    const float* __restrict__ Wotd, const float* __restrict__ botd,
    const float* __restrict__ lng, const float* __restrict__ lnb,
    float* __restrict__ td, float* __restrict__ out_tissue)
{
  __shared__ float s_cwn[TCH][NH_ * HH];
  __shared__ float s_a[TCH][HH];
  __shared__ float s_tu[TCH][HH];
  __shared__ float s_tmp[TCH][HH];
  __shared__ float s_red[2][4];
  __shared__ float s_dinv[TCH][NH_];
  int t0 = blockIdx.x * TCH;
  int j = threadIdx.x;
  int h = j >> 5;

  if (j < TCH * NH_) {
    int t = j >> 3, hh = j & 7;
    int s0 = soff[t0 + t], s1 = soff[t0 + t + 1];
    float d = 0.f;
    for (int q = s0; q < s1; q++) d += Pbuf[(size_t)q * PSTRIDE + 2048 + hh];
    s_dinv[t][hh] = (s1 > s0) ? 1.f / d : 0.f;
  }
  __syncthreads();

  for (int e = j; e < TCH * NH_ * HH; e += 256) {
    int t = e >> 11, c = e & 2047, hh = c >> 8;
    int s0 = soff[t0 + t], s1 = soff[t0 + t + 1];
    float a = 0.f;
    for (int q = s0; q < s1; q++) a += Pbuf[(size_t)q * PSTRIDE + c];
    s_cwn[t][c] = a * s_dinv[t][hh];
  }
  __syncthreads();

  float acc[TCH];
  #pragma unroll
  for (int t = 0; t < TCH; t++) acc[t] = 0.f;
  for (int k = 0; k < HH; k++) {
    float w = Wv[(size_t)k * HH + j];
    #pragma unroll
    for (int t = 0; t < TCH; t++) acc[t] += s_cwn[t][h * HH + k] * w;
  }
  {
    float bj = bv[j];
    #pragma unroll
    for (int t = 0; t < TCH; t++) s_a[t][j] = acc[t] + bj;
  }
  __syncthreads();

  #pragma unroll
  for (int t = 0; t < TCH; t++) acc[t] = 0.f;
  for (int k = 0; k < HH; k++) {
    float w = Wo[(size_t)k * HH + j];
    #pragma unroll
    for (int t = 0; t < TCH; t++) acc[t] += s_a[t][k] * w;
  }
  {
    float bj = bo[j];
    #pragma unroll
    for (int t = 0; t < TCH; t++) {
      int tt = t0 + t;
      s_tu[t][j] = (counts[tt] > 0) ? (acc[t] + bj) : tissue[(size_t)tt * HH + j];
    }
  }
  __syncthreads();

  #pragma unroll
  for (int t = 0; t < TCH; t++) acc[t] = 0.f;
  for (int k = 0; k < HH; k++) {
    float w = Wvtd[(size_t)k * HH + j];
    #pragma unroll
    for (int t = 0; t < TCH; t++) acc[t] += s_tu[t][k] * w;
  }
  {
    float bj = bvtd[j];
    #pragma unroll
    for (int t = 0; t < TCH; t++) s_tmp[t][j] = acc[t] + bj;
  }
  __syncthreads();

  #pragma unroll
  for (int t = 0; t < TCH; t++) acc[t] = 0.f;
  for (int k = 0; k < HH; k++) {
    float w = Wotd[(size_t)k * HH + j];
    #pragma unroll
    for (int t = 0; t < TCH; t++) acc[t] += s_tmp[t][k] * w;
  }
  {
    float bj = botd[j];
    #pragma unroll
    for (int t = 0; t < TCH; t++) td[(size_t)(t0 + t) * HH + j] = acc[t] + bj;
  }

  float gj = lng[j], bj2 = lnb[j];
  for (int t = 0; t < TCH; t++) {
    float y = tissue[(size_t)(t0 + t) * HH + j] + s_tu[t][j];
    float s1 = y, s2 = y * y;
    #pragma unroll
    for (int d = 1; d < 64; d <<= 1) { s1 += __shfl_xor(s1, d, 64); s2 += __shfl_xor(s2, d, 64); }
    int wv_ = j >> 6, ln_ = j & 63;
    __syncthreads();
    if (ln_ == 0) { s_red[0][wv_] = s1; s_red[1][wv_] = s2; }
    __syncthreads();
    s1 = s_red[0][0] + s_red[0][1] + s_red[0][2] + s_red[0][3];
    s2 = s_red[1][0] + s_red[1][1] + s_red[1][2] + s_red[1][3];
    float mean = s1 * (1.f / 256.f);
    float var = s2 * (1.f / 256.f) - mean * mean;
    float inv = rsqrtf(var + EPS);
    out_tissue[(size_t)(t0 + t) * HH + j] = (y - mean) * inv * gj + bj2;
  }
}

// ---------------- final: cell_out = LN(cell + td[label]), grid-stride, 2-row ILP ----------------

#define COB 4096

__global__ __launch_bounds__(256) void k_cellout(
    const float* __restrict__ cell, const float* __restrict__ td,
    const int* __restrict__ labels,
    const float* __restrict__ lng, const float* __restrict__ lnb,
    float* __restrict__ out)
{
  int lane = threadIdx.x & 63;
  float4 gv = *reinterpret_cast<const float4*>(&lng[lane * 4]);
  float4 bvv = *reinterpret_cast<const float4*>(&lnb[lane * 4]);
  const int stride = COB * 4;
  int wid = blockIdx.x * 4 + (threadIdx.x >> 6);
  for (int row = wid; row < NC; row += 2 * stride) {
    int rowB = row + stride;
    bool hasB = rowB < NC;
    int cA = labels[row];
    float4 xA = *reinterpret_cast<const float4*>(&cell[(size_t)row * HH + lane * 4]);
    float4 uA = *reinterpret_cast<const float4*>(&td[(size_t)cA * HH + lane * 4]);
    float4 xB, uB;
    if (hasB) {
      int cB = labels[rowB];
      xB = *reinterpret_cast<const float4*>(&cell[(size_t)rowB * HH + lane * 4]);
      uB = *reinterpret_cast<const float4*>(&td[(size_t)cB * HH + lane * 4]);
    }
    {
      float y0 = xA.x + uA.x, y1 = xA.y + uA.y, y2 = xA.z + uA.z, y3 = xA.w + uA.w;
      float s1 = y0 + y1 + y2 + y3;
      float s2 = y0 * y0 + y1 * y1 + y2 * y2 + y3 * y3;
      #pragma unroll
      for (int d = 1; d < 64; d <<= 1) { s1 += __shfl_xor(s1, d, 64); s2 += __shfl_xor(s2, d, 64); }
      float mean = s1 * (1.f / 256.f);
      float var = s2 * (1.f / 256.f) - mean * mean;
      float inv = rsqrtf(var + EPS);
      float4 o;
      o.x = (y0 - mean) * inv * gv.x + bvv.x;
      o.y = (y1 - mean) * inv * gv.y + bvv.y;
      o.z = (y2 - mean) * inv * gv.z + bvv.z;
      o.w = (y3 - mean) * inv * gv.w + bvv.w;
      *reinterpret_cast<float4*>(&out[(size_t)row * HH + lane * 4]) = o;
    }
    if (hasB) {
      float y0 = xB.x + uB.x, y1 = xB.y + uB.y, y2 = xB.z + uB.z, y3 = xB.w + uB.w;
      float s1 = y0 + y1 + y2 + y3;
      float s2 = y0 * y0 + y1 * y1 + y2 * y2 + y3 * y3;
      #pragma unroll
      for (int d = 1; d < 64; d <<= 1) { s1 += __shfl_xor(s1, d, 64); s2 += __shfl_xor(s2, d, 64); }
      float mean = s1 * (1.f / 256.f);
      float var = s2 * (1.f / 256.f) - mean * mean;
      float inv = rsqrtf(var + EPS);
      float4 o;
      o.x = (y0 - mean) * inv * gv.x + bvv.x;
      o.y = (y1 - mean) * inv * gv.y + bvv.y;
      o.z = (y2 - mean) * inv * gv.z + bvv.z;
      o.w = (y3 - mean) * inv * gv.w + bvv.w;
      *reinterpret_cast<float4*>(&out[(size_t)rowB * HH + lane * 4]) = o;
    }
  }
}

// ---------------- launch ----------------

extern "C" void kernel_launch(void* const* d_in, const int* in_sizes, int n_in,
                              void* d_out, int out_size, void* d_ws, size_t ws_size,
                              hipStream_t stream) {
  const float* cell   = (const float*)d_in[0];
  const float* tissue = (const float*)d_in[1];
  const int*   labels = (const int*)d_in[2];
  const float* Wq = (const float*)d_in[4];  const float* bq = (const float*)d_in[5];
  const float* Wk = (const float*)d_in[6];  const float* bk = (const float*)d_in[7];
  const float* Wv = (const float*)d_in[8];  const float* bv = (const float*)d_in[9];
  const float* Wo = (const float*)d_in[10]; const float* bo = (const float*)d_in[11];
  const float* Wvtd = (const float*)d_in[12]; const float* bvtd = (const float*)d_in[13];
  const float* Wotd = (const float*)d_in[14]; const float* botd = (const float*)d_in[15];
  const float* lncg = (const float*)d_in[16]; const float* lncb = (const float*)d_in[17];
  const float* lntg = (const float*)d_in[18]; const float* lntb = (const float*)d_in[19];
  float* out_cell   = (float*)d_out;
  float* out_tissue = (float*)d_out + (size_t)NC * HH;

  char* w = (char*)d_ws;
  auto take = [&](size_t bytes) { void* p = (void*)w; w += (bytes + 255) & ~(size_t)255; return p; };
  int*   counts  = (int*)take((size_t)NT * 4);
  int*   cursor  = (int*)take((size_t)NT * 4);
  int*   offsets = (int*)take((size_t)(NT + 1) * 4);
  int*   soff    = (int*)take((size_t)(NT + 1) * 4);
  int*   slice_t = (int*)take((size_t)PSLICES * 4);
  float* Q       = (float*)take((size_t)NT * HH * 4);
  float* Qproj   = (float*)take((size_t)NT * NH_ * HH * 4);
  float* bkq     = (float*)take((size_t)NT * NH_ * 4);
  float* td      = (float*)take((size_t)NT * HH * 4);
  float* Pbuf    = (float*)take((size_t)PSLICES * PSTRIDE * 4);      // ~29 MB
  unsigned short* cellb = (unsigned short*)take((size_t)NC * HH * 2); // ~102 MB sorted bf16 rows

  hipMemsetAsync(counts, 0, 16384, stream);   // counts + cursor

  const int CB = (NC + 255) / 256;
  k_hist<<<CB, 256, 0, stream>>>(labels, counts);
  k_scan<<<1, 64, 0, stream>>>(counts, offsets, soff, slice_t);
  k_sortcvt<<<SCVB, 256, 0, stream>>>(cell, labels, offsets, cursor, cellb);

  k_gemm_bias<<<(NT + 15) / 16, 256, 0, stream>>>(tissue, Wq, bq, Q, NT);
  k_qproj<<<8 * ((NT + 63) / 64), 256, 0, stream>>>(Q, Wk, bk, Qproj, bkq);

  k_cellslice<<<PSLICES, 256, 0, stream>>>(cellb, offsets, soff, slice_t,
                                           Qproj, bkq, Pbuf);

  k_tissuechain<<<NT / TCH, 256, 0, stream>>>(tissue, counts, Pbuf, soff,
      Wv, bv, Wo, bo, Wvtd, bvtd, Wotd, botd, lntg, lntb, td, out_tissue);

  k_cellout<<<COB, 256, 0, stream>>>(cell, td, labels, lncg, lncb, out_cell);
}

// Round 9
// 431.911 us; speedup vs baseline: 1.0229x; 1.0080x over previous
//
#include <hip/hip_runtime.h>
#include <math.h>

#define NC 200000
#define NT 2000
#define HH 256
#define NH_ 8
#define SCALE 0.17677669529663687f   // 32^-0.5
#define EPS 1e-5f
#define SLICE 128
#define PSLICES (NT + NC / SLICE + 1)   // upper bound on slice count
#define PSTRIDE 2056                    // 2048 cw + 8 denom

// ---------------- zero counts+cursor (replaces 117us fillBufferAligned!) ----------------

__global__ void k_zero(int* __restrict__ p) {
  // zero 4096 ints = 16384 bytes (counts + cursor incl. padding)
  int i = threadIdx.x;
  #pragma unroll
  for (int k = 0; k < 16; k++) p[i + k * 256] = 0;
}

// ---------------- counting sort of cells by cluster ----------------

__global__ void k_hist(const int* __restrict__ labels, int* __restrict__ counts) {
  int i = blockIdx.x * 256 + threadIdx.x;
  if (i < NC) atomicAdd(&counts[labels[i]], 1);
}

// scan: offsets (cell prefix), soff (slice prefix) + slice_t map
__global__ void k_scan(const int* __restrict__ counts, int* __restrict__ offsets,
                       int* __restrict__ soff, int* __restrict__ slice_t) {
  int tid = threadIdx.x;
  int base = tid * 32;
  int la[32], lb[32], scnt[32];
  int sa = 0, sb = 0;
  #pragma unroll
  for (int k = 0; k < 32; k++) {
    int idx = base + k;
    int v = (idx < NT) ? counts[idx] : 0;
    la[k] = sa; lb[k] = sb;
    scnt[k] = (v + SLICE - 1) / SLICE;
    sa += v; sb += scnt[k];
  }
  int ia_ = sa, ib_ = sb;
  #pragma unroll
  for (int d = 1; d < 64; d <<= 1) {
    int oa = __shfl_up(ia_, d, 64);
    int ob = __shfl_up(ib_, d, 64);
    if (tid >= d) { ia_ += oa; ib_ += ob; }
  }
  int ea = ia_ - sa, eb = ib_ - sb;
  #pragma unroll
  for (int k = 0; k < 32; k++) {
    int idx = base + k;
    if (idx < NT) {
      offsets[idx] = ea + la[k];
      soff[idx] = eb + lb[k];
      int st = eb + lb[k];
      for (int s2 = 0; s2 < scnt[k]; s2++) slice_t[st + s2] = idx;
    }
  }
  if (tid == 63) { offsets[NT] = ia_; soff[NT] = ib_; }
}

// ---------------- bf16 pack/unpack ----------------

__device__ inline unsigned pk2(float a, float b) {
  unsigned ua = (__float_as_uint(a) + 0x8000u) >> 16;
  unsigned ub = (__float_as_uint(b) + 0x8000u) & 0xFFFF0000u;
  return ua | ub;
}
__device__ inline float lo16(unsigned u) { return __uint_as_float(u << 16); }
__device__ inline float hi16(unsigned u) { return __uint_as_float(u & 0xFFFF0000u); }

// ---------------- sort+convert: coalesced read, bf16 scatter-write to sorted order ----------------

#define SCVB 2048

__global__ __launch_bounds__(256) void k_sortcvt(
    const float* __restrict__ cell, const int* __restrict__ labels,
    const int* __restrict__ offsets, int* __restrict__ cursor,
    unsigned short* __restrict__ cellb)
{
  int lane = threadIdx.x & 63;
  int w = blockIdx.x * 4 + (threadIdx.x >> 6);
  const int nw = SCVB * 4;
  for (int i = w; i < NC; i += nw) {
    int pos = 0;
    if (lane == 0) {
      int c = labels[i];
      pos = offsets[c] + atomicAdd(&cursor[c], 1);
    }
    pos = __shfl(pos, 0, 64);
    float4 x = *reinterpret_cast<const float4*>(&cell[(size_t)i * HH + lane * 4]);
    uint2 o;
    o.x = pk2(x.x, x.y);
    o.y = pk2(x.z, x.w);
    *reinterpret_cast<uint2*>(&cellb[(size_t)pos * HH + lane * 4]) = o;
  }
}

// ---------------- small GEMM: C[M,256] = A[M,256] @ W[256,256] + bias ----------------

__global__ __launch_bounds__(256) void k_gemm_bias(
    const float* __restrict__ A, const float* __restrict__ W,
    const float* __restrict__ bias, float* __restrict__ C, int M)
{
  __shared__ float Al[16][33];
  __shared__ float Wl[32][HH];
  int tid = threadIdx.x;
  int r0 = blockIdx.x * 16;
  float acc[16];
  #pragma unroll
  for (int r = 0; r < 16; r++) acc[r] = 0.f;
  for (int k0 = 0; k0 < HH; k0 += 32) {
    for (int e = tid; e < 16 * 32; e += 256) {
      int r = e >> 5, k = e & 31;
      int row = r0 + r;
      Al[r][k] = (row < M) ? A[(size_t)row * HH + k0 + k] : 0.f;
    }
    for (int e = tid; e < 32 * HH; e += 256) {
      int k = e >> 8, j = e & 255;
      Wl[k][j] = W[(size_t)(k0 + k) * HH + j];
    }
    __syncthreads();
    for (int k = 0; k < 32; k++) {
      float w = Wl[k][tid];
      #pragma unroll
      for (int r = 0; r < 16; r++) acc[r] += Al[r][k] * w;
    }
    __syncthreads();
  }
  float bj = bias[tid];
  #pragma unroll
  for (int r = 0; r < 16; r++) {
    int row = r0 + r;
    if (row < M) C[(size_t)row * HH + tid] = acc[r] + bj;
  }
}

// ---------------- Qproj + bkq (fused) ----------------

__global__ __launch_bounds__(256) void k_qproj(
    const float* __restrict__ Q, const float* __restrict__ Wk,
    const float* __restrict__ bk, float* __restrict__ Qproj,
    float* __restrict__ bkq)
{
  __shared__ float Al[64][33];
  __shared__ float Bl[32][257];
  int h = blockIdx.x & 7, tb = blockIdx.x >> 3;
  int t0 = tb * 64;
  int tid = threadIdx.x;
  for (int e = tid; e < 64 * 32; e += 256) {
    int r = e >> 5, d = e & 31;
    int t = t0 + r;
    Al[r][d] = (t < NT) ? Q[(size_t)t * HH + h * 32 + d] * SCALE : 0.f;
  }
  for (int e = tid; e < 256 * 32; e += 256) {
    int j = e >> 5, d = e & 31;
    Bl[d][j] = Wk[(size_t)j * HH + h * 32 + d];
  }
  __syncthreads();
  float acc[64];
  #pragma unroll
  for (int r = 0; r < 64; r++) acc[r] = 0.f;
  for (int d = 0; d < 32; d++) {
    float b = Bl[d][tid];
    #pragma unroll
    for (int r = 0; r < 64; r++) acc[r] += Al[r][d] * b;
  }
  for (int r = 0; r < 64; r++) {
    int t = t0 + r;
    if (t < NT) Qproj[((size_t)t * NH_ + h) * HH + tid] = acc[r];
  }
  if (tid < 64) {
    int t = t0 + tid;
    if (t < NT) {
      float s = 0.f;
      #pragma unroll
      for (int d = 0; d < 32; d++) s += Al[tid][d] * bk[h * 32 + d];
      bkq[t * NH_ + h] = s;
    }
  }
}

// ---------------- per-slice attention: CONTIGUOUS bf16 rows, register-resident ----------------

__global__ __launch_bounds__(256) void k_cellslice(
    const unsigned short* __restrict__ cellb,
    const int* __restrict__ offsets, const int* __restrict__ soff,
    const int* __restrict__ slice_t,
    const float* __restrict__ Qproj, const float* __restrict__ bkq,
    float* __restrict__ Pbuf)
{
  __shared__ float cwlds[NH_][HH];
  __shared__ float red[4][NH_];

  int s = blockIdx.x;
  if (s >= soff[NT]) return;
  int t = slice_t[s];
  int l = s - soff[t];
  int c0 = offsets[t] + l * SLICE;
  int c1 = min(c0 + SLICE, offsets[t + 1]);
  int nc = c1 - c0;

  int tid = threadIdx.x;
  int w = tid >> 6, lane = tid & 63;
  int hg = lane & 3, kc = lane >> 2;

  const float* qpb = Qproj + (size_t)t * NH_ * HH;
  float4 qp0[4], qp1[4];
  #pragma unroll
  for (int i = 0; i < 4; i++) {
    qp0[i] = *reinterpret_cast<const float4*>(qpb + (2 * hg) * HH + (i * 16 + kc) * 4);
    qp1[i] = *reinterpret_cast<const float4*>(qpb + (2 * hg + 1) * HH + (i * 16 + kc) * 4);
  }
  float bq0 = bkq[t * NH_ + 2 * hg];
  float bq1 = bkq[t * NH_ + 2 * hg + 1];

  float4 cw0[4], cw1[4];
  #pragma unroll
  for (int i = 0; i < 4; i++) {
    cw0[i] = make_float4(0.f, 0.f, 0.f, 0.f);
    cw1[i] = make_float4(0.f, 0.f, 0.f, 0.f);
  }
  float d0 = 0.f, d1 = 0.f;

  uint2 xv[4], nv[4];
  {
    const uint2* p = reinterpret_cast<const uint2*>(cellb + (size_t)(c0 + min(w, nc - 1)) * HH);
    #pragma unroll
    for (int i = 0; i < 4; i++) xv[i] = p[i * 16 + kc];
  }

  for (int ic = w; ic < nc; ic += 4) {
    int icn = min(ic + 4, nc - 1);
    const uint2* pn = reinterpret_cast<const uint2*>(cellb + (size_t)(c0 + icn) * HH);
    #pragma unroll
    for (int i = 0; i < 4; i++) nv[i] = pn[i * 16 + kc];

    float4 x[4];
    #pragma unroll
    for (int i = 0; i < 4; i++)
      x[i] = make_float4(lo16(xv[i].x), hi16(xv[i].x), lo16(xv[i].y), hi16(xv[i].y));

    float s0 = 0.f, s1 = 0.f;
    #pragma unroll
    for (int i = 0; i < 4; i++) {
      s0 += x[i].x * qp0[i].x + x[i].y * qp0[i].y + x[i].z * qp0[i].z + x[i].w * qp0[i].w;
      s1 += x[i].x * qp1[i].x + x[i].y * qp1[i].y + x[i].z * qp1[i].z + x[i].w * qp1[i].w;
    }
    #pragma unroll
    for (int d = 4; d < 64; d <<= 1) {
      s0 += __shfl_xor(s0, d, 64);
      s1 += __shfl_xor(s1, d, 64);
    }
    float e0 = __expf(s0 + bq0);
    float e1 = __expf(s1 + bq1);
    d0 += e0; d1 += e1;
    #pragma unroll
    for (int i = 0; i < 4; i++) {
      cw0[i].x += e0 * x[i].x; cw0[i].y += e0 * x[i].y;
      cw0[i].z += e0 * x[i].z; cw0[i].w += e0 * x[i].w;
      cw1[i].x += e1 * x[i].x; cw1[i].y += e1 * x[i].y;
      cw1[i].z += e1 * x[i].z; cw1[i].w += e1 * x[i].w;
    }
    #pragma unroll
    for (int i = 0; i < 4; i++) xv[i] = nv[i];
  }

  // merge 4 waves' cw into LDS
  if (w == 0) {
    #pragma unroll
    for (int i = 0; i < 4; i++) {
      *reinterpret_cast<float4*>(&cwlds[2 * hg][(i * 16 + kc) * 4]) = cw0[i];
      *reinterpret_cast<float4*>(&cwlds[2 * hg + 1][(i * 16 + kc) * 4]) = cw1[i];
    }
  }
  if (kc == 0) { red[w][2 * hg] = d0; red[w][2 * hg + 1] = d1; }
  __syncthreads();
  #pragma unroll
  for (int ww = 1; ww < 4; ww++) {
    if (w == ww) {
      #pragma unroll
      for (int i = 0; i < 4; i++) {
        float4 a = *reinterpret_cast<float4*>(&cwlds[2 * hg][(i * 16 + kc) * 4]);
        a.x += cw0[i].x; a.y += cw0[i].y; a.z += cw0[i].z; a.w += cw0[i].w;
        *reinterpret_cast<float4*>(&cwlds[2 * hg][(i * 16 + kc) * 4]) = a;
        float4 b = *reinterpret_cast<float4*>(&cwlds[2 * hg + 1][(i * 16 + kc) * 4]);
        b.x += cw1[i].x; b.y += cw1[i].y; b.z += cw1[i].z; b.w += cw1[i].w;
        *reinterpret_cast<float4*>(&cwlds[2 * hg + 1][(i * 16 + kc) * 4]) = b;
      }
    }
    __syncthreads();
  }

  float* pb = Pbuf + (size_t)s * PSTRIDE;
  #pragma unroll
  for (int h = 0; h < NH_; h++) pb[h * HH + tid] = cwlds[h][tid];
  if (tid < NH_) pb[2048 + tid] = red[0][tid] + red[1][tid] + red[2][tid] + red[3][tid];
}

// ---------------- fused tissue chain (with slice reduction) ----------------

#define TCH 4

__global__ __launch_bounds__(256) void k_tissuechain(
    const float* __restrict__ tissue, const int* __restrict__ counts,
    const float* __restrict__ Pbuf, const int* __restrict__ soff,
    const float* __restrict__ Wv, const float* __restrict__ bv,
    const float* __restrict__ Wo, const float* __restrict__ bo,
    const float* __restrict__ Wvtd, const float* __restrict__ bvtd,
    const float* __restrict__ Wotd, const float* __restrict__ botd,
    const float* __restrict__ lng, const float* __restrict__ lnb,
    float* __restrict__ td, float* __restrict__ out_tissue)
{
  __shared__ float s_cwn[TCH][NH_ * HH];
  __shared__ float s_a[TCH][HH];
  __shared__ float s_tu[TCH][HH];
  __shared__ float s_tmp[TCH][HH];
  __shared__ float s_red[2][4];
  __shared__ float s_dinv[TCH][NH_];
  int t0 = blockIdx.x * TCH;
  int j = threadIdx.x;
  int h = j >> 5;

  if (j < TCH * NH_) {
    int t = j >> 3, hh = j & 7;
    int s0 = soff[t0 + t], s1 = soff[t0 + t + 1];
    float d = 0.f;
    for (int q = s0; q < s1; q++) d += Pbuf[(size_t)q * PSTRIDE + 2048 + hh];
    s_dinv[t][hh] = (s1 > s0) ? 1.f / d : 0.f;
  }
  __syncthreads();

  for (int e = j; e < TCH * NH_ * HH; e += 256) {
    int t = e >> 11, c = e & 2047, hh = c >> 8;
    int s0 = soff[t0 + t], s1 = soff[t0 + t + 1];
    float a = 0.f;
    for (int q = s0; q < s1; q++) a += Pbuf[(size_t)q * PSTRIDE + c];
    s_cwn[t][c] = a * s_dinv[t][hh];
  }
  __syncthreads();

  float acc[TCH];
  #pragma unroll
  for (int t = 0; t < TCH; t++) acc[t] = 0.f;
  for (int k = 0; k < HH; k++) {
    float w = Wv[(size_t)k * HH + j];
    #pragma unroll
    for (int t = 0; t < TCH; t++) acc[t] += s_cwn[t][h * HH + k] * w;
  }
  {
    float bj = bv[j];
    #pragma unroll
    for (int t = 0; t < TCH; t++) s_a[t][j] = acc[t] + bj;
  }
  __syncthreads();

  #pragma unroll
  for (int t = 0; t < TCH; t++) acc[t] = 0.f;
  for (int k = 0; k < HH; k++) {
    float w = Wo[(size_t)k * HH + j];
    #pragma unroll
    for (int t = 0; t < TCH; t++) acc[t] += s_a[t][k] * w;
  }
  {
    float bj = bo[j];
    #pragma unroll
    for (int t = 0; t < TCH; t++) {
      int tt = t0 + t;
      s_tu[t][j] = (counts[tt] > 0) ? (acc[t] + bj) : tissue[(size_t)tt * HH + j];
    }
  }
  __syncthreads();

  #pragma unroll
  for (int t = 0; t < TCH; t++) acc[t] = 0.f;
  for (int k = 0; k < HH; k++) {
    float w = Wvtd[(size_t)k * HH + j];
    #pragma unroll
    for (int t = 0; t < TCH; t++) acc[t] += s_tu[t][k] * w;
  }
  {
    float bj = bvtd[j];
    #pragma unroll
    for (int t = 0; t < TCH; t++) s_tmp[t][j] = acc[t] + bj;
  }
  __syncthreads();

  #pragma unroll
  for (int t = 0; t < TCH; t++) acc[t] = 0.f;
  for (int k = 0; k < HH; k++) {
    float w = Wotd[(size_t)k * HH + j];
    #pragma unroll
    for (int t = 0; t < TCH; t++) acc[t] += s_tmp[t][k] * w;
  }
  {
    float bj = botd[j];
    #pragma unroll
    for (int t = 0; t < TCH; t++) td[(size_t)(t0 + t) * HH + j] = acc[t] + bj;
  }

  float gj = lng[j], bj2 = lnb[j];
  for (int t = 0; t < TCH; t++) {
    float y = tissue[(size_t)(t0 + t) * HH + j] + s_tu[t][j];
    float s1 = y, s2 = y * y;
    #pragma unroll
    for (int d = 1; d < 64; d <<= 1) { s1 += __shfl_xor(s1, d, 64); s2 += __shfl_xor(s2, d, 64); }
    int wv_ = j >> 6, ln_ = j & 63;
    __syncthreads();
    if (ln_ == 0) { s_red[0][wv_] = s1; s_red[1][wv_] = s2; }
    __syncthreads();
    s1 = s_red[0][0] + s_red[0][1] + s_red[0][2] + s_red[0][3];
    s2 = s_red[1][0] + s_red[1][1] + s_red[1][2] + s_red[1][3];
    float mean = s1 * (1.f / 256.f);
    float var = s2 * (1.f / 256.f) - mean * mean;
    float inv = rsqrtf(var + EPS);
    out_tissue[(size_t)(t0 + t) * HH + j] = (y - mean) * inv * gj + bj2;
  }
}

// ---------------- final: cell_out = LN(cell + td[label]), grid-stride, 2-row ILP ----------------

#define COB 4096

__global__ __launch_bounds__(256) void k_cellout(
    const float* __restrict__ cell, const float* __restrict__ td,
    const int* __restrict__ labels,
    const float* __restrict__ lng, const float* __restrict__ lnb,
    float* __restrict__ out)
{
  int lane = threadIdx.x & 63;
  float4 gv = *reinterpret_cast<const float4*>(&lng[lane * 4]);
  float4 bvv = *reinterpret_cast<const float4*>(&lnb[lane * 4]);
  const int stride = COB * 4;
  int wid = blockIdx.x * 4 + (threadIdx.x >> 6);
  for (int row = wid; row < NC; row += 2 * stride) {
    int rowB = row + stride;
    bool hasB = rowB < NC;
    int cA = labels[row];
    float4 xA = *reinterpret_cast<const float4*>(&cell[(size_t)row * HH + lane * 4]);
    float4 uA = *reinterpret_cast<const float4*>(&td[(size_t)cA * HH + lane * 4]);
    float4 xB, uB;
    if (hasB) {
      int cB = labels[rowB];
      xB = *reinterpret_cast<const float4*>(&cell[(size_t)rowB * HH + lane * 4]);
      uB = *reinterpret_cast<const float4*>(&td[(size_t)cB * HH + lane * 4]);
    }
    {
      float y0 = xA.x + uA.x, y1 = xA.y + uA.y, y2 = xA.z + uA.z, y3 = xA.w + uA.w;
      float s1 = y0 + y1 + y2 + y3;
      float s2 = y0 * y0 + y1 * y1 + y2 * y2 + y3 * y3;
      #pragma unroll
      for (int d = 1; d < 64; d <<= 1) { s1 += __shfl_xor(s1, d, 64); s2 += __shfl_xor(s2, d, 64); }
      float mean = s1 * (1.f / 256.f);
      float var = s2 * (1.f / 256.f) - mean * mean;
      float inv = rsqrtf(var + EPS);
      float4 o;
      o.x = (y0 - mean) * inv * gv.x + bvv.x;
      o.y = (y1 - mean) * inv * gv.y + bvv.y;
      o.z = (y2 - mean) * inv * gv.z + bvv.z;
      o.w = (y3 - mean) * inv * gv.w + bvv.w;
      *reinterpret_cast<float4*>(&out[(size_t)row * HH + lane * 4]) = o;
    }
    if (hasB) {
      float y0 = xB.x + uB.x, y1 = xB.y + uB.y, y2 = xB.z + uB.z, y3 = xB.w + uB.w;
      float s1 = y0 + y1 + y2 + y3;
      float s2 = y0 * y0 + y1 * y1 + y2 * y2 + y3 * y3;
      #pragma unroll
      for (int d = 1; d < 64; d <<= 1) { s1 += __shfl_xor(s1, d, 64); s2 += __shfl_xor(s2, d, 64); }
      float mean = s1 * (1.f / 256.f);
      float var = s2 * (1.f / 256.f) - mean * mean;
      float inv = rsqrtf(var + EPS);
      float4 o;
      o.x = (y0 - mean) * inv * gv.x + bvv.x;
      o.y = (y1 - mean) * inv * gv.y + bvv.y;
      o.z = (y2 - mean) * inv * gv.z + bvv.z;
      o.w = (y3 - mean) * inv * gv.w + bvv.w;
      *reinterpret_cast<float4*>(&out[(size_t)rowB * HH + lane * 4]) = o;
    }
  }
}

// ---------------- launch ----------------

extern "C" void kernel_launch(void* const* d_in, const int* in_sizes, int n_in,
                              void* d_out, int out_size, void* d_ws, size_t ws_size,
                              hipStream_t stream) {
  const float* cell   = (const float*)d_in[0];
  const float* tissue = (const float*)d_in[1];
  const int*   labels = (const int*)d_in[2];
  const float* Wq = (const float*)d_in[4];  const float* bq = (const float*)d_in[5];
  const float* Wk = (const float*)d_in[6];  const float* bk = (const float*)d_in[7];
  const float* Wv = (const float*)d_in[8];  const float* bv = (const float*)d_in[9];
  const float* Wo = (const float*)d_in[10]; const float* bo = (const float*)d_in[11];
  const float* Wvtd = (const float*)d_in[12]; const float* bvtd = (const float*)d_in[13];
  const float* Wotd = (const float*)d_in[14]; const float* botd = (const float*)d_in[15];
  const float* lncg = (const float*)d_in[16]; const float* lncb = (const float*)d_in[17];
  const float* lntg = (const float*)d_in[18]; const float* lntb = (const float*)d_in[19];
  float* out_cell   = (float*)d_out;
  float* out_tissue = (float*)d_out + (size_t)NC * HH;

  char* w = (char*)d_ws;
  auto take = [&](size_t bytes) { void* p = (void*)w; w += (bytes + 255) & ~(size_t)255; return p; };
  int*   counts  = (int*)take((size_t)NT * 4);
  int*   cursor  = (int*)take((size_t)NT * 4);
  int*   offsets = (int*)take((size_t)(NT + 1) * 4);
  int*   soff    = (int*)take((size_t)(NT + 1) * 4);
  int*   slice_t = (int*)take((size_t)PSLICES * 4);
  float* Q       = (float*)take((size_t)NT * HH * 4);
  float* Qproj   = (float*)take((size_t)NT * NH_ * HH * 4);
  float* bkq     = (float*)take((size_t)NT * NH_ * 4);
  float* td      = (float*)take((size_t)NT * HH * 4);
  float* Pbuf    = (float*)take((size_t)PSLICES * PSTRIDE * 4);      // ~29 MB
  unsigned short* cellb = (unsigned short*)take((size_t)NC * HH * 2); // ~102 MB sorted bf16 rows

  k_zero<<<1, 256, 0, stream>>>(counts);   // counts + cursor (16 KB contiguous)

  const int CB = (NC + 255) / 256;
  k_hist<<<CB, 256, 0, stream>>>(labels, counts);
  k_scan<<<1, 64, 0, stream>>>(counts, offsets, soff, slice_t);
  k_sortcvt<<<SCVB, 256, 0, stream>>>(cell, labels, offsets, cursor, cellb);

  k_gemm_bias<<<(NT + 15) / 16, 256, 0, stream>>>(tissue, Wq, bq, Q, NT);
  k_qproj<<<8 * ((NT + 63) / 64), 256, 0, stream>>>(Q, Wk, bk, Qproj, bkq);

  k_cellslice<<<PSLICES, 256, 0, stream>>>(cellb, offsets, soff, slice_t,
                                           Qproj, bkq, Pbuf);

  k_tissuechain<<<NT / TCH, 256, 0, stream>>>(tissue, counts, Pbuf, soff,
      Wv, bv, Wo, bo, Wvtd, bvtd, Wotd, botd, lntg, lntb, td, out_tissue);

  k_cellout<<<COB, 256, 0, stream>>>(cell, td, labels, lncg, lncb, out_cell);
}